// Round 8
// baseline (2761.927 us; speedup 1.0000x reference)
//
#include <hip/hip_runtime.h>

#define B_  128
#define T_  4096
#define F_  64
#define H_  128
#define NT  512   // 8 waves; wave w owns cols 16w..16w+15 of each gate
#define XGS 516   // xg tau-row stride in dwords (516%32=4 -> 2-way write aliasing = free)

typedef _Float16 half8_t __attribute__((ext_vector_type(8)));
typedef _Float16 half2_t __attribute__((ext_vector_type(2)));
typedef float    f32x4   __attribute__((ext_vector_type(4)));

__device__ __forceinline__ half2_t pack2(float a, float b) {
  half2_t r; r[0] = (_Float16)a; r[1] = (_Float16)b; return r;
}

// LDS-only barrier (no vmcnt drain; global x loads stay in flight).
__device__ __forceinline__ void wg_barrier() {
  __asm__ volatile("s_waitcnt lgkmcnt(0)\n\ts_barrier" ::: "memory");
}

__device__ __forceinline__ float fast_sigmoid(float x) {
  float e = __builtin_amdgcn_exp2f(x * -1.4426950408889634f);
  return __builtin_amdgcn_rcpf(1.0f + e);
}
__device__ __forceinline__ float fast_tanh(float x) {
  float e = __builtin_amdgcn_exp2f(x * -2.8853900817779268f);
  return 2.0f * __builtin_amdgcn_rcpf(1.0f + e) - 1.0f;
}

// Per step only the h-part (16 mfma/wave). Wih*x + bias batched over time:
// every 16 steps an M=16 (16 timesteps) GEMM -> xg in LDS (fp32), spread one
// gate per tau over taus 0..3 (A-frags preloaded at tau 15 of prior period).
// Global X(P+2) loaded at tau 4, staged to LDS f16 at tau 8.
__global__ __launch_bounds__(NT, 2) void lstm_xg2_kernel(
    const float* __restrict__ X,    // [B, T, F]
    const float* __restrict__ Wih,  // [4H, F]
    const float* __restrict__ Whh,  // [4H, H]
    const float* __restrict__ bih,  // [4H]
    const float* __restrict__ bhh,  // [4H]
    float* __restrict__ out)        // [B, H]
{
  const int tid  = threadIdx.x;
  const int b    = blockIdx.x;
  const int lane = tid & 63;
  const int w    = tid >> 6;     // wave 0..7
  const int lg   = lane >> 4;    // k-group / tau-group 0..3
  const int lc   = lane & 15;    // col-in-16 (tau row in batch GEMM A)

  __shared__ __align__(16) _Float16 hbuf[2][H_];        // h ring (f16)
  __shared__ __align__(16) _Float16 xst[2][16 * 72];    // staged x, 16 tau x 64(+8 pad) f16
  __shared__ __align__(16) float    xg[2][16 * XGS];    // xg[tau][col*4+gate] fp32

  // ---- B-frags: Wf[g][c]; lane holds W[128g + 16w + lc][32c + 8lg + j],
  // j=0..7 (c=0..3 -> Whh, c=4..5 -> Wih), f32 -> f16.
  half8_t Wf[4][6];
  f32x4   xinit[4];   // bias, C-init of batch GEMM (same for all tau rows)
#pragma unroll
  for (int g = 0; g < 4; ++g) {
    const int row = 128 * g + 16 * w + lc;
    const float bv = bih[row] + bhh[row];
    f32x4 bi = {bv, bv, bv, bv};
    xinit[g] = bi;
#pragma unroll
    for (int c = 0; c < 6; ++c) {
      const float* src = (c < 4) ? (Whh + (size_t)row * H_ + 32 * c + 8 * lg)
                                 : (Wih + (size_t)row * F_ + 32 * (c - 4) + 8 * lg);
      float4 lo = *(const float4*)(src);
      float4 hi = *(const float4*)(src + 4);
      half8_t v;
      v[0] = (_Float16)lo.x; v[1] = (_Float16)lo.y;
      v[2] = (_Float16)lo.z; v[3] = (_Float16)lo.w;
      v[4] = (_Float16)hi.x; v[5] = (_Float16)hi.y;
      v[6] = (_Float16)hi.z; v[7] = (_Float16)hi.w;
      Wf[g][c] = v;
    }
  }

  const float* xbase = X + (size_t)b * T_ * F_;
  const int    tp    = tid >> 5;   // tau row this thread stages
  const int    kp    = tid & 31;   // f32-pair within row

  // ---- prologue: stage X(period 0) and X(period 1) to LDS f16
  {
    float2 v0 = ((const float2*)xbase)[0 * 512 + tid];
    float2 v1 = ((const float2*)xbase)[1 * 512 + tid];
    *(half2_t*)&xst[0][tp * 72 + 2 * kp] = pack2(v0.x, v0.y);
    *(half2_t*)&xst[1][tp * 72 + 2 * kp] = pack2(v1.x, v1.y);
  }
  wg_barrier();   // xst[0], xst[1] visible

  const f32x4 zf = {0.0f, 0.0f, 0.0f, 0.0f};

  // ---- GEMM xg(0) from xst[0] -> xg[0]
  {
    half8_t a0 = *(const half8_t*)&xst[0][lc * 72 + 8 * lg];
    half8_t a1 = *(const half8_t*)&xst[0][lc * 72 + 32 + 8 * lg];
#pragma unroll
    for (int g = 0; g < 4; ++g) {
      f32x4 ab = __builtin_amdgcn_mfma_f32_16x16x32_f16(a0, Wf[g][4], xinit[g], 0, 0, 0);
      ab       = __builtin_amdgcn_mfma_f32_16x16x32_f16(a1, Wf[g][5], ab, 0, 0, 0);
#pragma unroll
      for (int r = 0; r < 4; ++r)
        xg[0][(4 * lg + r) * XGS + (16 * w + lc) * 4 + g] = ab[r];
    }
  }
  // A-frags for period 0's spread GEMM (xg(1) from xst[1])
  half8_t ga0 = *(const half8_t*)&xst[1][lc * 72 + 8 * lg];
  half8_t ga1 = *(const half8_t*)&xst[1][lc * 72 + 32 + 8 * lg];
  wg_barrier();   // xg[0] visible

  f32x4 pre[4], pB[4];
#pragma unroll
  for (int g = 0; g < 4; ++g) { pre[g] = zf; pB[g] = zf; }
  f32x4 xg4 = *(const f32x4*)&xg[0][0 * XGS + (16 * w + lc) * 4];   // t=0

  float cs = 0.0f, hl = 0.0f;
  float2 xv = {0.0f, 0.0f};

#pragma unroll 2
  for (int t = 0; t < T_; ++t) {
    const int buf = t & 1;
    const int P   = t >> 4;
    const int tau = t & 15;

    // ---- activation: preact = h-part (pre+pB) + xg (bias folded in)
    float si = fast_sigmoid(pre[0][0] + pB[0][0] + xg4[0]);
    float sf = fast_sigmoid(pre[1][0] + pB[1][0] + xg4[1]);
    float sg = fast_tanh   (pre[2][0] + pB[2][0] + xg4[2]);
    float so = fast_sigmoid(pre[3][0] + pB[3][0] + xg4[3]);

    cs = sf * cs + si * sg;
    float hn = so * fast_tanh(cs);
    hl = hn;

    if (lane < 16) hbuf[buf][16 * w + lc] = (_Float16)hn;

    // ---- periodic work, smoothed (all branches wave-uniform)
    if (tau < 4) {
      // one gate of the xg(P+1) GEMM per tau; ga0/ga1 preloaded at tau 15
      const int sb = (P + 1) & 1;
      const int g  = tau;
      f32x4 ab = __builtin_amdgcn_mfma_f32_16x16x32_f16(ga0, Wf[g][4], xinit[g], 0, 0, 0);
      ab       = __builtin_amdgcn_mfma_f32_16x16x32_f16(ga1, Wf[g][5], ab, 0, 0, 0);
#pragma unroll
      for (int r = 0; r < 4; ++r)
        xg[sb][(4 * lg + r) * XGS + (16 * w + lc) * 4 + g] = ab[r];
    } else if (tau == 4) {
      // issue global loads for X(P+2); staged at tau 8
      int Pn = P + 2; if (Pn > (T_ / 16 - 1)) Pn = T_ / 16 - 1;
      xv = ((const float2*)xbase)[(size_t)Pn * 512 + tid];
    } else if (tau == 8) {
      // stage X(P+2) into xst[P&1] (X(P) is dead)
      *(half2_t*)&xst[P & 1][tp * 72 + 2 * kp] = pack2(xv.x, xv.y);
    } else if (tau == 15) {
      // preload A-frags for next period's spread GEMM (xst written at tau 8)
      const int sn = P & 1;   // xst[(P+2)&1] == xst[P&1]
      ga0 = *(const half8_t*)&xst[sn][lc * 72 + 8 * lg];
      ga1 = *(const half8_t*)&xst[sn][lc * 72 + 32 + 8 * lg];
    }

    // ---- xg prefetch for t+1, PRE-barrier (target buffer last written >=12
    // barriers ago: taus 0..3 write the other parity; safe at every tau)
    {
      const int tn = t + 1;
      xg4 = *(const f32x4*)&xg[(tn >> 4) & 1][(tn & 15) * XGS + (16 * w + lc) * 4];
    }

    wg_barrier();   // h_t (+ periodic xg/xst writes) visible

    // ---- post-barrier: h-frag reads, then 8 independent + 8 dependent mfmas
    half8_t ah0 = *(const half8_t*)&hbuf[buf][ 0 + 8 * lg];
    half8_t ah1 = *(const half8_t*)&hbuf[buf][32 + 8 * lg];
    half8_t ah2 = *(const half8_t*)&hbuf[buf][64 + 8 * lg];
    half8_t ah3 = *(const half8_t*)&hbuf[buf][96 + 8 * lg];

    f32x4 aA[4], aB[4];
#pragma unroll
    for (int g = 0; g < 4; ++g)
      aA[g] = __builtin_amdgcn_mfma_f32_16x16x32_f16(ah0, Wf[g][0], zf, 0, 0, 0);
#pragma unroll
    for (int g = 0; g < 4; ++g)
      aB[g] = __builtin_amdgcn_mfma_f32_16x16x32_f16(ah2, Wf[g][2], zf, 0, 0, 0);
#pragma unroll
    for (int g = 0; g < 4; ++g)
      pre[g] = __builtin_amdgcn_mfma_f32_16x16x32_f16(ah1, Wf[g][1], aA[g], 0, 0, 0);
#pragma unroll
    for (int g = 0; g < 4; ++g)
      pB[g]  = __builtin_amdgcn_mfma_f32_16x16x32_f16(ah3, Wf[g][3], aB[g], 0, 0, 0);
  }

  if (lane < 16) out[(size_t)b * H_ + 16 * w + lc] = hl;
}

extern "C" void kernel_launch(void* const* d_in, const int* in_sizes, int n_in,
                              void* d_out, int out_size, void* d_ws, size_t ws_size,
                              hipStream_t stream) {
  const float* X   = (const float*)d_in[0];
  const float* Wih = (const float*)d_in[1];
  const float* Whh = (const float*)d_in[2];
  const float* bih = (const float*)d_in[3];
  const float* bhh = (const float*)d_in[4];
  float* out = (float*)d_out;

  lstm_xg2_kernel<<<dim3(B_), dim3(NT), 0, stream>>>(X, Wih, Whh, bih, bhh, out);
}

// Round 9
// 2042.495 us; speedup vs baseline: 1.3522x; 1.3522x over previous
//
#include <hip/hip_runtime.h>

#define B_  128
#define T_  4096
#define F_  64
#define H_  128
#define NT  512   // 8 waves; wave w owns cols 16w..16w+15 of each gate
#define XGS 516   // xg tau-row stride (dw): 4-way store aliasing (was 8-way at 512)

typedef _Float16 half8_t __attribute__((ext_vector_type(8)));
typedef _Float16 half2_t __attribute__((ext_vector_type(2)));
typedef float    f32x4   __attribute__((ext_vector_type(4)));

__device__ __forceinline__ half2_t pack2(float a, float b) {
  half2_t r; r[0] = (_Float16)a; r[1] = (_Float16)b; return r;
}

// LDS-only barrier (no vmcnt drain; global x loads stay in flight).
__device__ __forceinline__ void wg_barrier() {
  __asm__ volatile("s_waitcnt lgkmcnt(0)\n\ts_barrier" ::: "memory");
}

__device__ __forceinline__ float fast_sigmoid(float x) {
  float e = __builtin_amdgcn_exp2f(x * -1.4426950408889634f);
  return __builtin_amdgcn_rcpf(1.0f + e);
}
__device__ __forceinline__ float fast_tanh(float x) {
  float e = __builtin_amdgcn_exp2f(x * -2.8853900817779268f);
  return 2.0f * __builtin_amdgcn_rcpf(1.0f + e) - 1.0f;
}

// Per step only the h-part (16 mfma/wave). Wih*x + bias batched over time:
// every 16 steps an M=16 (16 timesteps) GEMM -> xg in LDS (fp32) at tau==0,
// with A-frags preloaded at tau 15 of the prior period (STATIC gate indexing
// only -- dynamic register-array indexing spills to scratch, R8 post-mortem).
// Global X(P+2) loaded at tau 0, staged to LDS f16 at tau 8.
__global__ __launch_bounds__(NT, 2) void lstm_xg3_kernel(
    const float* __restrict__ X,    // [B, T, F]
    const float* __restrict__ Wih,  // [4H, F]
    const float* __restrict__ Whh,  // [4H, H]
    const float* __restrict__ bih,  // [4H]
    const float* __restrict__ bhh,  // [4H]
    float* __restrict__ out)        // [B, H]
{
  const int tid  = threadIdx.x;
  const int b    = blockIdx.x;
  const int lane = tid & 63;
  const int w    = tid >> 6;     // wave 0..7
  const int lg   = lane >> 4;    // k-group / tau-group 0..3
  const int lc   = lane & 15;    // col-in-16 (tau row in batch GEMM A)

  __shared__ __align__(16) _Float16 hbuf[2][H_];        // h ring (f16)
  __shared__ __align__(16) _Float16 xst[2][16 * 72];    // staged x, 16 tau x 64(+8 pad) f16
  __shared__ __align__(16) float    xg[2][16 * XGS];    // xg[tau][col*4+gate] fp32

  // ---- B-frags: Wf[g][c]; lane holds W[128g + 16w + lc][32c + 8lg + j],
  // j=0..7 (c=0..3 -> Whh, c=4..5 -> Wih), f32 -> f16.
  half8_t Wf[4][6];
  f32x4   xinit[4];   // bias, C-init of batch GEMM (same for all tau rows)
#pragma unroll
  for (int g = 0; g < 4; ++g) {
    const int row = 128 * g + 16 * w + lc;
    const float bv = bih[row] + bhh[row];
    f32x4 bi = {bv, bv, bv, bv};
    xinit[g] = bi;
#pragma unroll
    for (int c = 0; c < 6; ++c) {
      const float* src = (c < 4) ? (Whh + (size_t)row * H_ + 32 * c + 8 * lg)
                                 : (Wih + (size_t)row * F_ + 32 * (c - 4) + 8 * lg);
      float4 lo = *(const float4*)(src);
      float4 hi = *(const float4*)(src + 4);
      half8_t v;
      v[0] = (_Float16)lo.x; v[1] = (_Float16)lo.y;
      v[2] = (_Float16)lo.z; v[3] = (_Float16)lo.w;
      v[4] = (_Float16)hi.x; v[5] = (_Float16)hi.y;
      v[6] = (_Float16)hi.z; v[7] = (_Float16)hi.w;
      Wf[g][c] = v;
    }
  }

  const float* xbase = X + (size_t)b * T_ * F_;
  const int    tp    = tid >> 5;   // tau row this thread stages
  const int    kp    = tid & 31;   // f32-pair within row

  // ---- prologue: stage X(period 0) and X(period 1) to LDS f16
  {
    float2 v0 = ((const float2*)xbase)[0 * 512 + tid];
    float2 v1 = ((const float2*)xbase)[1 * 512 + tid];
    *(half2_t*)&xst[0][tp * 72 + 2 * kp] = pack2(v0.x, v0.y);
    *(half2_t*)&xst[1][tp * 72 + 2 * kp] = pack2(v1.x, v1.y);
  }
  wg_barrier();   // xst[0], xst[1] visible

  const f32x4 zf = {0.0f, 0.0f, 0.0f, 0.0f};

  // ---- GEMM xg(0) from xst[0] -> xg[0]  (static g indices)
  {
    half8_t a0 = *(const half8_t*)&xst[0][lc * 72 + 8 * lg];
    half8_t a1 = *(const half8_t*)&xst[0][lc * 72 + 32 + 8 * lg];
#pragma unroll
    for (int g = 0; g < 4; ++g) {
      f32x4 ab = __builtin_amdgcn_mfma_f32_16x16x32_f16(a0, Wf[g][4], xinit[g], 0, 0, 0);
      ab       = __builtin_amdgcn_mfma_f32_16x16x32_f16(a1, Wf[g][5], ab, 0, 0, 0);
#pragma unroll
      for (int r = 0; r < 4; ++r)
        xg[0][(4 * lg + r) * XGS + (16 * w + lc) * 4 + g] = ab[r];
    }
  }
  // A-frags for period 0's tau-0 GEMM (xg(1) from xst[1])
  half8_t ga0 = *(const half8_t*)&xst[1][lc * 72 + 8 * lg];
  half8_t ga1 = *(const half8_t*)&xst[1][lc * 72 + 32 + 8 * lg];
  wg_barrier();   // xg[0] visible

  f32x4 pre[4], pB[4];
#pragma unroll
  for (int g = 0; g < 4; ++g) { pre[g] = zf; pB[g] = zf; }
  f32x4 xg4 = *(const f32x4*)&xg[0][0 * XGS + (16 * w + lc) * 4];   // t=0

  float cs = 0.0f, hl = 0.0f;
  float2 xv = {0.0f, 0.0f};

#pragma unroll 2
  for (int t = 0; t < T_; ++t) {
    const int buf = t & 1;
    const int P   = t >> 4;
    const int tau = t & 15;

    // ---- activation: preact = h-part (pre+pB) + xg (bias folded in)
    float si = fast_sigmoid(pre[0][0] + pB[0][0] + xg4[0]);
    float sf = fast_sigmoid(pre[1][0] + pB[1][0] + xg4[1]);
    float sg = fast_tanh   (pre[2][0] + pB[2][0] + xg4[2]);
    float so = fast_sigmoid(pre[3][0] + pB[3][0] + xg4[3]);

    cs = sf * cs + si * sg;
    float hn = so * fast_tanh(cs);
    hl = hn;

    if (lane < 16) hbuf[buf][16 * w + lc] = (_Float16)hn;

    // ---- periodic work (wave-uniform branches, static indices everywhere)
    if (tau == 0) {
      // batch GEMM xg(P+1) from preloaded ga0/ga1 (read at tau 15 last period)
      const int sb = (P + 1) & 1;
#pragma unroll
      for (int g = 0; g < 4; ++g) {
        f32x4 ab = __builtin_amdgcn_mfma_f32_16x16x32_f16(ga0, Wf[g][4], xinit[g], 0, 0, 0);
        ab       = __builtin_amdgcn_mfma_f32_16x16x32_f16(ga1, Wf[g][5], ab, 0, 0, 0);
#pragma unroll
        for (int r = 0; r < 4; ++r)
          xg[sb][(4 * lg + r) * XGS + (16 * w + lc) * 4 + g] = ab[r];
      }
      // issue global loads for X(P+2); staged at tau 8
      int Pn = P + 2; if (Pn > (T_ / 16 - 1)) Pn = T_ / 16 - 1;
      xv = ((const float2*)xbase)[(size_t)Pn * 512 + tid];
    } else if (tau == 8) {
      // stage X(P+2) into xst[P&1] (X(P) is dead)
      *(half2_t*)&xst[P & 1][tp * 72 + 2 * kp] = pack2(xv.x, xv.y);
    } else if (tau == 15) {
      // preload A-frags for next period's tau-0 GEMM (xst stable since tau 8)
      ga0 = *(const half8_t*)&xst[P & 1][lc * 72 + 8 * lg];
      ga1 = *(const half8_t*)&xst[P & 1][lc * 72 + 32 + 8 * lg];
    }

    // ---- xg prefetch for t+1, PRE-barrier (target parity last written >=11
    // barriers ago at every tau; wg_barrier drains lgkm before next use)
    {
      const int tn = t + 1;
      xg4 = *(const f32x4*)&xg[(tn >> 4) & 1][(tn & 15) * XGS + (16 * w + lc) * 4];
    }

    wg_barrier();   // h_t (+ periodic xg/xst writes) visible

    // ---- post-barrier: h-frag reads, then 8 independent + 8 dependent mfmas
    half8_t ah0 = *(const half8_t*)&hbuf[buf][ 0 + 8 * lg];
    half8_t ah1 = *(const half8_t*)&hbuf[buf][32 + 8 * lg];
    half8_t ah2 = *(const half8_t*)&hbuf[buf][64 + 8 * lg];
    half8_t ah3 = *(const half8_t*)&hbuf[buf][96 + 8 * lg];

    f32x4 aA[4], aB[4];
#pragma unroll
    for (int g = 0; g < 4; ++g)
      aA[g] = __builtin_amdgcn_mfma_f32_16x16x32_f16(ah0, Wf[g][0], zf, 0, 0, 0);
#pragma unroll
    for (int g = 0; g < 4; ++g)
      aB[g] = __builtin_amdgcn_mfma_f32_16x16x32_f16(ah2, Wf[g][2], zf, 0, 0, 0);
#pragma unroll
    for (int g = 0; g < 4; ++g)
      pre[g] = __builtin_amdgcn_mfma_f32_16x16x32_f16(ah1, Wf[g][1], aA[g], 0, 0, 0);
#pragma unroll
    for (int g = 0; g < 4; ++g)
      pB[g]  = __builtin_amdgcn_mfma_f32_16x16x32_f16(ah3, Wf[g][3], aB[g], 0, 0, 0);
  }

  if (lane < 16) out[(size_t)b * H_ + 16 * w + lc] = hl;
}

extern "C" void kernel_launch(void* const* d_in, const int* in_sizes, int n_in,
                              void* d_out, int out_size, void* d_ws, size_t ws_size,
                              hipStream_t stream) {
  const float* X   = (const float*)d_in[0];
  const float* Wih = (const float*)d_in[1];
  const float* Whh = (const float*)d_in[2];
  const float* bih = (const float*)d_in[3];
  const float* bhh = (const float*)d_in[4];
  float* out = (float*)d_out;

  lstm_xg3_kernel<<<dim3(B_), dim3(NT), 0, stream>>>(X, Wih, Whh, bih, bhh, out);
}